// Round 7
// baseline (485.244 us; speedup 1.0000x reference)
//
#include <hip/hip_runtime.h>
#include <hip/hip_bf16.h>

// VAE_RNN: B=4096, T=200, D=128, L=64, H=128, CIN=2L+D=256
// Persistent-block RNN, 256 blocks x 512 threads, 16 rows/block = TWO 8-row
// streams (alpha rows 0-7, beta rows 8-15) ping-ponged through a specialized
// 2-group pipeline so NO phase is idle:
//   I1: G0 A(a)      || G1 C(b,t-1)
//   I2: G0 B(a)      || G1 D(b,t-1) + x(b,t) LDS write
//   I3: G0 A(b)      || G1 C(a)
//   I4: G0 B(b)      || G1 D(a)     + x(a,t+1) LDS write
// G0 = waves 0-3 (GEMMs A,B; ~230 VGPR incl. weights), G1 = waves 4-7 (C,D).
// MFMA tiles are 16 rows; each stream's rows 8-15 are garbage (row-confined,
// finite, never stored). State y,s lives fp32 in G1 registers; B's r-waves
// read y,s as bf16 from the h tile (written by D). No ys_lds at all.
// lgkm-only barriers keep global x prefetch in flight across phases.

#define NB 4096
#define NT 200
#define ND 128
#define HS 528      // h/t row stride (bytes) ; 528/16=33 -> conflict-free b128
#define TS 272      // tn row stride (bytes)

typedef __bf16 bf16;
typedef __attribute__((ext_vector_type(8))) __bf16 bf16x8;
typedef __attribute__((ext_vector_type(4))) __bf16 bf16x4;
typedef __attribute__((ext_vector_type(4))) float f32x4;

#define BAR() asm volatile("s_waitcnt lgkmcnt(0)\n\ts_barrier" ::: "memory")

__device__ __forceinline__ f32x4 mfma16(bf16x8 a, bf16x8 b, f32x4 c){
    return __builtin_amdgcn_mfma_f32_16x16x32_bf16(a, b, c, 0, 0, 0);
}
// inf-safe, branch-free
__device__ __forceinline__ float fast_tanh(float x){
    float e = __expf(2.f * x);
    return 1.f - 2.f * __builtin_amdgcn_rcpf(e + 1.f);
}
__device__ __forceinline__ float fast_sigmoid(float x){
    return __builtin_amdgcn_rcpf(1.f + __expf(-x));
}
__device__ __forceinline__ bf16x4 tanh4(f32x4 a){
    bf16x4 o;
    o[0] = (bf16)fast_tanh(a[0]);
    o[1] = (bf16)fast_tanh(a[1]);
    o[2] = (bf16)fast_tanh(a[2]);
    o[3] = (bf16)fast_tanh(a[3]);
    return o;
}
__device__ __forceinline__ f32x4 bias4(const float* b, int f){
    f32x4 r; r[0] = b[f]; r[1] = b[f+1]; r[2] = b[f+2]; r[3] = b[f+3]; return r;
}

__global__ __launch_bounds__(512, 2)
void vae_rnn(const float* __restrict__ data,
             const float* __restrict__ ug_w1, const float* __restrict__ ug_b1,
             const float* __restrict__ ug_w2, const float* __restrict__ ug_b2,
             const float* __restrict__ rg_w1, const float* __restrict__ rg_b1,
             const float* __restrict__ rg_w2, const float* __restrict__ rg_b2,
             const float* __restrict__ ns_w1, const float* __restrict__ ns_b1,
             const float* __restrict__ ns_w2, const float* __restrict__ ns_b2,
             float* __restrict__ out)
{
    __shared__ __align__(16) char h_lds [2][16 * HS];  // [y|s|x] per stream
    __shared__ __align__(16) char t_lds [2][16 * HS];  // tanh(l1) [ug|rg]
    __shared__ __align__(16) char tn_lds[2][16 * TS];  // tanh(l1) ns
    __shared__ float u_lds[2][16][68];                 // u gate fp32

    const int tid  = threadIdx.x;
    const int wave = tid >> 6;
    const int lane = tid & 63;
    const int lq   = lane >> 4;
    const int lc   = lane & 15;          // batch row within tile (>=8: garbage)
    const int row0 = blockIdx.x * 16;

    // -------- prologue: zero h tiles, write x(0) for both streams --------
    for (int i = tid; i < 2*16*HS/16; i += 512){
        bf16x8 z = {};
        *(bf16x8*)(&h_lds[0][0] + i*16) = z;
    }
    if (tid < 256){
        int sr = tid >> 7, pr0 = (tid >> 4) & 7, pc0 = tid & 15;
        const float* xs = data + (size_t)(row0 + sr*8 + pr0) * (NT*ND) + pc0*8;
        float4 a0 = *(const float4*)xs;
        float4 a1 = *(const float4*)(xs + 4);
        bf16x8 xv = { (bf16)a0.x,(bf16)a0.y,(bf16)a0.z,(bf16)a0.w,
                      (bf16)a1.x,(bf16)a1.y,(bf16)a1.z,(bf16)a1.w };
        *(bf16x8*)(&h_lds[sr][0] + pr0*HS + 256 + pc0*16) = xv;
    }
    __syncthreads();

    if (wave < 4){
        // ===================== G0: GEMMs A and B =====================
        const int  w  = wave;
        const bool UR = (w < 2);          // u-gate role (else r-gate)
        const int  f1 = (w & 1) * 64;     // A output feats within gate W1
        const int  f2 = (w & 1) * 32;     // B output feats within gate
        const float* W1 = UR ? ug_w1 : rg_w1;
        const float* B1 = UR ? ug_b1 : rg_b1;
        const float* W2 = UR ? ug_w2 : rg_w2;
        const float* B2 = UR ? ug_b2 : rg_b2;

        bf16x8 wA[32]; f32x4 bA[4];
        #pragma unroll
        for (int j = 0; j < 4; ++j){
            int n = f1 + j*16 + lc;
            bA[j] = bias4(B1, f1 + j*16 + lq*4);
            #pragma unroll
            for (int kt = 0; kt < 8; ++kt){
                bf16x8 f;
                #pragma unroll
                for (int e = 0; e < 8; ++e) f[e] = (bf16)W1[(kt*32 + lq*8 + e)*128 + n];
                wA[kt*4 + j] = f;
            }
        }
        bf16x8 wB[8]; f32x4 bB[2];
        #pragma unroll
        for (int j = 0; j < 2; ++j){
            int n = f2 + j*16 + lc;
            bB[j] = bias4(B2, f2 + j*16 + lq*4);
            #pragma unroll
            for (int kt = 0; kt < 4; ++kt){
                bf16x8 f;
                #pragma unroll
                for (int e = 0; e < 8; ++e) f[e] = (bf16)W2[(kt*32 + lq*8 + e)*64 + n];
                wB[kt*2 + j] = f;
            }
        }

        const int hrd = lc*HS + lq*16;                 // + kt*64
        const int twr = lc*HS + w*128 + lq*8;          // + j*32
        const int trd = lc*HS + lq*16 + (UR ? 0 : 256);
        const int yso = lc*HS + 2*(f2 + lq*4);         // y cols; +128B = s cols
        const int uco = f2 + lq*4;

        #pragma unroll 1
        for (int t = 0; t < NT; ++t){
            #pragma unroll
            for (int ph = 0; ph < 2; ++ph){            // ph0: stream a, ph1: b
                char* hb = &h_lds[ph][0];
                char* tb = &t_lds[ph][0];
                // ---- A(stream ph): t = tanh(h @ W1 + b1) ----
                f32x4 a0 = bA[0], a1 = bA[1], a2 = bA[2], a3 = bA[3];
                #pragma unroll
                for (int kt = 0; kt < 8; ++kt){
                    bf16x8 hv = *(const bf16x8*)(hb + hrd + kt*64);
                    a0 = mfma16(wA[kt*4+0], hv, a0);
                    a1 = mfma16(wA[kt*4+1], hv, a1);
                    a2 = mfma16(wA[kt*4+2], hv, a2);
                    a3 = mfma16(wA[kt*4+3], hv, a3);
                }
                *(bf16x4*)(tb + twr +  0) = tanh4(a0);
                *(bf16x4*)(tb + twr + 32) = tanh4(a1);
                *(bf16x4*)(tb + twr + 64) = tanh4(a2);
                *(bf16x4*)(tb + twr + 96) = tanh4(a3);
                BAR();
                // ---- B(stream ph): u|r = sigmoid(t_half @ W2 + b2) ----
                bf16x4 yb0, yb1, sb0, sb1;
                if (!UR){
                    yb0 = *(const bf16x4*)(hb + yso);
                    yb1 = *(const bf16x4*)(hb + yso + 32);
                    sb0 = *(const bf16x4*)(hb + yso + 128);
                    sb1 = *(const bf16x4*)(hb + yso + 160);
                }
                f32x4 b0 = bB[0], b1 = bB[1];
                #pragma unroll
                for (int kt = 0; kt < 4; ++kt){
                    bf16x8 tv = *(const bf16x8*)(tb + trd + kt*64);
                    b0 = mfma16(wB[kt*2+0], tv, b0);
                    b1 = mfma16(wB[kt*2+1], tv, b1);
                }
                float g00 = fast_sigmoid(b0[0]), g01 = fast_sigmoid(b0[1]);
                float g02 = fast_sigmoid(b0[2]), g03 = fast_sigmoid(b0[3]);
                float g10 = fast_sigmoid(b1[0]), g11 = fast_sigmoid(b1[1]);
                float g12 = fast_sigmoid(b1[2]), g13 = fast_sigmoid(b1[3]);
                if (UR){
                    *(float4*)&u_lds[ph][lc][uco]      = make_float4(g00,g01,g02,g03);
                    *(float4*)&u_lds[ph][lc][uco + 16] = make_float4(g10,g11,g12,g13);
                } else {
                    bf16x4 hy0 = { (bf16)((float)yb0[0]*g00), (bf16)((float)yb0[1]*g01),
                                   (bf16)((float)yb0[2]*g02), (bf16)((float)yb0[3]*g03) };
                    bf16x4 hy1 = { (bf16)((float)yb1[0]*g10), (bf16)((float)yb1[1]*g11),
                                   (bf16)((float)yb1[2]*g12), (bf16)((float)yb1[3]*g13) };
                    bf16x4 hs0 = { (bf16)((float)sb0[0]*g00), (bf16)((float)sb0[1]*g01),
                                   (bf16)((float)sb0[2]*g02), (bf16)((float)sb0[3]*g03) };
                    bf16x4 hs1 = { (bf16)((float)sb1[0]*g10), (bf16)((float)sb1[1]*g11),
                                   (bf16)((float)sb1[2]*g12), (bf16)((float)sb1[3]*g13) };
                    *(bf16x4*)(hb + yso +   0) = hy0;
                    *(bf16x4*)(hb + yso +  32) = hy1;
                    *(bf16x4*)(hb + yso + 128) = hs0;
                    *(bf16x4*)(hb + yso + 160) = hs1;
                }
                BAR();
            }
        }
        BAR();   // matches G1's epilogue barrier
    } else {
        // ===================== G1: GEMMs C and D =====================
        const int  g   = wave - 4;
        const bool STD = (g >= 2);        // D role: std (abs) vs mean

        bf16x8 wC[16]; f32x4 bC[2];
        #pragma unroll
        for (int j = 0; j < 2; ++j){
            int n = g*32 + j*16 + lc;
            bC[j] = bias4(ns_b1, g*32 + j*16 + lq*4);
            #pragma unroll
            for (int kt = 0; kt < 8; ++kt){
                bf16x8 f;
                #pragma unroll
                for (int e = 0; e < 8; ++e) f[e] = (bf16)ns_w1[(kt*32 + lq*8 + e)*128 + n];
                wC[kt*2 + j] = f;
            }
        }
        bf16x8 wD[8]; f32x4 bD[2];
        #pragma unroll
        for (int j = 0; j < 2; ++j){
            int n = g*32 + j*16 + lc;
            bD[j] = bias4(ns_b2, g*32 + j*16 + lq*4);
            #pragma unroll
            for (int kt = 0; kt < 4; ++kt){
                bf16x8 f;
                #pragma unroll
                for (int e = 0; e < 8; ++e) f[e] = (bf16)ns_w2[(kt*32 + lq*8 + e)*128 + n];
                wD[kt*2 + j] = f;
            }
        }

        const int hrd = lc*HS + lq*16;            // + kt*64
        const int tnw = lc*TS + g*64 + lq*8;      // + j*32
        const int tnr = lc*TS + lq*16;            // + kt*64
        const int hyw = lc*HS + g*64 + lq*8;      // new y/s bf16
        const int uco = (g & 1)*32 + lq*4;
        const bool XW = (g < 2);                  // waves 4,5 own x traffic
        const int  pr = (tid & 127) >> 4;         // 0..7
        const int  pc = tid & 15;
        const float* xsA = data + (size_t)(row0 + pr)     * (NT*ND) + pc*8;
        const float* xsB = data + (size_t)(row0 + 8 + pr) * (NT*ND) + pc*8;
        char* xwA = &h_lds[0][0] + pr*HS + 256 + pc*16;
        char* xwB = &h_lds[1][0] + pr*HS + 256 + pc*16;

        f32x4 st0[2], st1[2];                     // fp32 state y|s per stream
        st0[0] = (f32x4){0,0,0,0}; st0[1] = (f32x4){0,0,0,0};
        st1[0] = (f32x4){0,0,0,0}; st1[1] = (f32x4){0,0,0,0};

        #pragma unroll 1
        for (int t = 0; t < NT; ++t){
            float4 xa0, xa1, xb0, xb1;
            if (XW){
                int t1 = (t + 1 < NT) ? (t + 1) : (NT - 1);
                xa0 = *(const float4*)(xsA + (size_t)t1*ND);
                xa1 = *(const float4*)(xsA + (size_t)t1*ND + 4);
                xb0 = *(const float4*)(xsB + (size_t)t*ND);
                xb1 = *(const float4*)(xsB + (size_t)t*ND + 4);
            }
            #pragma unroll
            for (int ph = 0; ph < 2; ++ph){
                const int sg = 1 - ph;            // C/D stream: b then a
                char* hb  = &h_lds[sg][0];
                char* tnb = &tn_lds[sg][0];
                const bool act = (ph == 1) || (t > 0);
                // ---- C(sg): tn = tanh(hc @ ns_w1 + b) ----
                if (act){
                    f32x4 c0 = bC[0], c1 = bC[1];
                    #pragma unroll
                    for (int kt = 0; kt < 8; ++kt){
                        bf16x8 hv = *(const bf16x8*)(hb + hrd + kt*64);
                        c0 = mfma16(wC[kt*2+0], hv, c0);
                        c1 = mfma16(wC[kt*2+1], hv, c1);
                    }
                    *(bf16x4*)(tnb + tnw +  0) = tanh4(c0);
                    *(bf16x4*)(tnb + tnw + 32) = tanh4(c1);
                }
                BAR();
                // ---- D(sg): ns; EMA in registers; publish bf16 y/s ----
                if (act){
                    f32x4 u4a = *(const f32x4*)&u_lds[sg][lc][uco];
                    f32x4 u4b = *(const f32x4*)&u_lds[sg][lc][uco + 16];
                    f32x4 d0 = bD[0], d1 = bD[1];
                    #pragma unroll
                    for (int kt = 0; kt < 4; ++kt){
                        bf16x8 tv = *(const bf16x8*)(tnb + tnr + kt*64);
                        d0 = mfma16(wD[kt*2+0], tv, d0);
                        d1 = mfma16(wD[kt*2+1], tv, d1);
                    }
                    #pragma unroll
                    for (int i = 0; i < 4; ++i){
                        float v0 = STD ? fabsf(d0[i]) : d0[i];
                        float v1 = STD ? fabsf(d1[i]) : d1[i];
                        st0[sg][i] = fmaf(u4a[i], st0[sg][i] - v0, v0);
                        st1[sg][i] = fmaf(u4b[i], st1[sg][i] - v1, v1);
                    }
                    bf16x4 hn0 = { (bf16)st0[sg][0], (bf16)st0[sg][1],
                                   (bf16)st0[sg][2], (bf16)st0[sg][3] };
                    bf16x4 hn1 = { (bf16)st1[sg][0], (bf16)st1[sg][1],
                                   (bf16)st1[sg][2], (bf16)st1[sg][3] };
                    *(bf16x4*)(hb + hyw +  0) = hn0;
                    *(bf16x4*)(hb + hyw + 32) = hn1;
                }
                if (XW){
                    if (ph == 0){
                        bf16x8 xv = { (bf16)xb0.x,(bf16)xb0.y,(bf16)xb0.z,(bf16)xb0.w,
                                      (bf16)xb1.x,(bf16)xb1.y,(bf16)xb1.z,(bf16)xb1.w };
                        *(bf16x8*)xwB = xv;
                    } else {
                        bf16x8 xv = { (bf16)xa0.x,(bf16)xa0.y,(bf16)xa0.z,(bf16)xa0.w,
                                      (bf16)xa1.x,(bf16)xa1.y,(bf16)xa1.z,(bf16)xa1.w };
                        *(bf16x8*)xwA = xv;
                    }
                }
                BAR();
            }
        }
        // -------- epilogue: finish stream b's step 199 (C then D) --------
        {
            char* hb  = &h_lds[1][0];
            char* tnb = &tn_lds[1][0];
            f32x4 c0 = bC[0], c1 = bC[1];
            #pragma unroll
            for (int kt = 0; kt < 8; ++kt){
                bf16x8 hv = *(const bf16x8*)(hb + hrd + kt*64);
                c0 = mfma16(wC[kt*2+0], hv, c0);
                c1 = mfma16(wC[kt*2+1], hv, c1);
            }
            *(bf16x4*)(tnb + tnw +  0) = tanh4(c0);
            *(bf16x4*)(tnb + tnw + 32) = tanh4(c1);
            BAR();
            f32x4 u4a = *(const f32x4*)&u_lds[1][lc][uco];
            f32x4 u4b = *(const f32x4*)&u_lds[1][lc][uco + 16];
            f32x4 d0 = bD[0], d1 = bD[1];
            #pragma unroll
            for (int kt = 0; kt < 4; ++kt){
                bf16x8 tv = *(const bf16x8*)(tnb + tnr + kt*64);
                d0 = mfma16(wD[kt*2+0], tv, d0);
                d1 = mfma16(wD[kt*2+1], tv, d1);
            }
            #pragma unroll
            for (int i = 0; i < 4; ++i){
                float v0 = STD ? fabsf(d0[i]) : d0[i];
                float v1 = STD ? fabsf(d1[i]) : d1[i];
                st0[1][i] = fmaf(u4a[i], st0[1][i] - v0, v0);
                st1[1][i] = fmaf(u4b[i], st1[1][i] - v1, v1);
            }
        }
        // -------- output from registers: yT then sT (fp32) --------
        if (lc < 8){
            size_t grA = (size_t)(row0 + lc);
            size_t grB = (size_t)(row0 + 8 + lc);
            int f = (g & 1)*32 + lq*4;
            float* base = STD ? (out + (size_t)NB*64) : out;
            *(float4*)&base[grA*64 + f]      = make_float4(st0[0][0],st0[0][1],st0[0][2],st0[0][3]);
            *(float4*)&base[grA*64 + f + 16] = make_float4(st1[0][0],st1[0][1],st1[0][2],st1[0][3]);
            *(float4*)&base[grB*64 + f]      = make_float4(st0[1][0],st0[1][1],st0[1][2],st0[1][3]);
            *(float4*)&base[grB*64 + f + 16] = make_float4(st1[1][0],st1[1][1],st1[1][2],st1[1][3]);
        }
    }
}

extern "C" void kernel_launch(void* const* d_in, const int* in_sizes, int n_in,
                              void* d_out, int out_size, void* d_ws, size_t ws_size,
                              hipStream_t stream) {
    const float* data  = (const float*)d_in[0];
    // d_in[1] = time_steps — unused by the reference computation
    const float* ug_w1 = (const float*)d_in[2];
    const float* ug_b1 = (const float*)d_in[3];
    const float* ug_w2 = (const float*)d_in[4];
    const float* ug_b2 = (const float*)d_in[5];
    const float* rg_w1 = (const float*)d_in[6];
    const float* rg_b1 = (const float*)d_in[7];
    const float* rg_w2 = (const float*)d_in[8];
    const float* rg_b2 = (const float*)d_in[9];
    const float* ns_w1 = (const float*)d_in[10];
    const float* ns_b1 = (const float*)d_in[11];
    const float* ns_w2 = (const float*)d_in[12];
    const float* ns_b2 = (const float*)d_in[13];

    hipLaunchKernelGGL(vae_rnn, dim3(NB/16), dim3(512), 0, stream,
                       data, ug_w1, ug_b1, ug_w2, ug_b2,
                       rg_w1, rg_b1, rg_w2, rg_b2,
                       ns_w1, ns_b1, ns_w2, ns_b2,
                       (float*)d_out);
}

// Round 8
// 324.002 us; speedup vs baseline: 1.4977x; 1.4977x over previous
//
#include <hip/hip_runtime.h>
#include <hip/hip_bf16.h>

// VAE_RNN: B=4096, T=200, D=128, L=64, H=128, CIN=2L+D=256
// Persistent-block RNN, 256 blocks x 512 threads (8 symmetric waves),
// 16 rows/block, 200 steps. Weights register-resident (128 VGPR/wave).
// KEY IDEA: A and C split into ys-part (state-dependent, critical path) and
// x-part (state-independent). x(t+1) is staged one step early, so A_x(t+1)
// and C_x(t+1) run in the latency shadows of P2/P3 and carry across the step
// boundary IN ACCUMULATOR REGISTERS (MFMA C-operand = the carry; batch-row ->
// lane mapping unchanged, so no permutes, no LDS).
//   P1: A_ys(t) [4kt, acc init = carried A_x(t)+bias] -> tanh -> t_lds
//       + publish x(t+1) to h, prefetch x(t+2) from HBM
//   P2: B(t) [4kt] -> sigmoid; u-waves: u in regs + u_lds; r-waves: hc=y*r,s*r
//       written IN PLACE over y,s cols; + xf reads + A_x(t+1) [8 MFMA]
//   P3: C_hc(t) [4kt, acc init = carried C_x(t)+bias] -> tanh -> tn_lds
//       + C_x(t+1) [4 MFMA on cached xf]
//   P4: D(t) [4kt] -> EMA in fp32 regs -> publish y,s bf16 to h
// 4 lgkm-only barriers/step; hc reuses y,s storage; u/state/x-partials in regs.

#define NB 4096
#define NT 200
#define ND 128
#define HS 528      // h/t row stride bytes (132 dw = 4 mod 32 -> benign 2-way)
#define TS 272      // tn row stride bytes

typedef __bf16 bf16;
typedef __attribute__((ext_vector_type(8))) __bf16 bf16x8;
typedef __attribute__((ext_vector_type(4))) __bf16 bf16x4;
typedef __attribute__((ext_vector_type(4))) float f32x4;

#define BAR() asm volatile("s_waitcnt lgkmcnt(0)\n\ts_barrier" ::: "memory")

__device__ __forceinline__ f32x4 mfma16(bf16x8 a, bf16x8 b, f32x4 c){
    return __builtin_amdgcn_mfma_f32_16x16x32_bf16(a, b, c, 0, 0, 0);
}
// inf-safe, branch-free
__device__ __forceinline__ float fast_tanh(float x){
    float e = __expf(2.f * x);
    return 1.f - 2.f * __builtin_amdgcn_rcpf(e + 1.f);
}
__device__ __forceinline__ float fast_sigmoid(float x){
    return __builtin_amdgcn_rcpf(1.f + __expf(-x));
}
__device__ __forceinline__ bf16x4 tanh4(f32x4 a){
    bf16x4 o;
    o[0] = (bf16)fast_tanh(a[0]);
    o[1] = (bf16)fast_tanh(a[1]);
    o[2] = (bf16)fast_tanh(a[2]);
    o[3] = (bf16)fast_tanh(a[3]);
    return o;
}
__device__ __forceinline__ f32x4 bias4(const float* b, int f){
    f32x4 r; r[0]=b[f]; r[1]=b[f+1]; r[2]=b[f+2]; r[3]=b[f+3]; return r;
}

__global__ __launch_bounds__(512, 2)
void vae_rnn(const float* __restrict__ data,
             const float* __restrict__ ug_w1, const float* __restrict__ ug_b1,
             const float* __restrict__ ug_w2, const float* __restrict__ ug_b2,
             const float* __restrict__ rg_w1, const float* __restrict__ rg_b1,
             const float* __restrict__ rg_w2, const float* __restrict__ rg_b2,
             const float* __restrict__ ns_w1, const float* __restrict__ ns_b1,
             const float* __restrict__ ns_w2, const float* __restrict__ ns_b2,
             float* __restrict__ out)
{
    __shared__ __align__(16) char h_lds [16 * HS];   // [y|s(->hc)|x(t+1)] bf16
    __shared__ __align__(16) char t_lds [16 * HS];   // tanh(l1) [ug|rg] bf16
    __shared__ __align__(16) char tn_lds[16 * TS];   // tanh(l1) ns bf16
    __shared__ float u_lds[16][68];                  // u gate fp32 (for std waves)

    const int tid  = threadIdx.x;
    const int w    = tid >> 6;
    const int lane = tid & 63;
    const int lq   = lane >> 4;
    const int lc   = lane & 15;          // batch row within tile
    const int row0 = blockIdx.x * 16;

    const bool UG = (w < 4);             // ug-gate side / u-role / mean-role
    const int fA = w * 32;               // A feats (256 over 8 waves)
    const int fB = (w & 3) * 16;         // B gate feats (64 per role)
    const int fC = w * 16;               // C feats (128 over 8 waves)
    const int fD = w * 16;               // D feats (mean 0:64, std 64:128)

    const float* W1 = UG ? ug_w1 : rg_w1;
    const float* B1 = UG ? ug_b1 : rg_b1;
    const float* W2 = UG ? ug_w2 : rg_w2;
    const float* B2 = UG ? ug_b2 : rg_b2;

    // ---------------- persistent weight fragments (128 VGPR) ----------------
    bf16x8 wAy[8], wAx[8]; f32x4 bA[2];
    #pragma unroll
    for (int j = 0; j < 2; ++j){
        int n = (fA + j*16 + lc) & 127;
        bA[j] = bias4(B1, (fA + j*16 + lq*4) & 127);
        #pragma unroll
        for (int kt = 0; kt < 4; ++kt){
            bf16x8 fy, fx;
            #pragma unroll
            for (int e = 0; e < 8; ++e){
                fy[e] = (bf16)W1[(      kt*32 + lq*8 + e)*128 + n];
                fx[e] = (bf16)W1[(128 + kt*32 + lq*8 + e)*128 + n];
            }
            wAy[kt*2 + j] = fy; wAx[kt*2 + j] = fx;
        }
    }
    bf16x8 wB[4]; f32x4 bB = bias4(B2, fB + lq*4);
    {
        int n = fB + lc;
        #pragma unroll
        for (int kt = 0; kt < 4; ++kt){
            bf16x8 f;
            #pragma unroll
            for (int e = 0; e < 8; ++e) f[e] = (bf16)W2[(kt*32 + lq*8 + e)*64 + n];
            wB[kt] = f;
        }
    }
    bf16x8 wCh[4], wCx[4]; f32x4 bC = bias4(ns_b1, fC + lq*4);
    {
        int n = fC + lc;
        #pragma unroll
        for (int kt = 0; kt < 4; ++kt){
            bf16x8 fh, fx;
            #pragma unroll
            for (int e = 0; e < 8; ++e){
                fh[e] = (bf16)ns_w1[(      kt*32 + lq*8 + e)*128 + n];
                fx[e] = (bf16)ns_w1[(128 + kt*32 + lq*8 + e)*128 + n];
            }
            wCh[kt] = fh; wCx[kt] = fx;
        }
    }
    bf16x8 wD[4]; f32x4 bD = bias4(ns_b2, fD + lq*4);
    {
        int n = fD + lc;
        #pragma unroll
        for (int kt = 0; kt < 4; ++kt){
            bf16x8 f;
            #pragma unroll
            for (int e = 0; e < 8; ++e) f[e] = (bf16)ns_w2[(kt*32 + lq*8 + e)*128 + n];
            wD[kt] = f;
        }
    }

    // ---------------- LDS pointers (loop-invariant) ----------------
    const char* h_ys_rd = h_lds + lc*HS + lq*16;          // + kt*64 (y,s / hc)
    const char* h_x_rd  = h_lds + lc*HS + 256 + lq*16;    // + kt*64 (x)
    char*       t_wr    = t_lds + lc*HS + 2*(fA + lq*4);  // + j*32
    const char* t_rd    = t_lds + lc*HS + lq*16 + (UG ? 0 : 256);
    char*       tn_wr   = tn_lds + lc*TS + 2*(fC + lq*4);
    const char* tn_rd   = tn_lds + lc*TS + lq*16;         // + kt*64
    char*       h_st_wr = h_lds + lc*HS + 2*(fD + lq*4);  // y/s publish (byte ok for fD>=64)
    char*       ys_rw   = h_lds + lc*HS + 2*(fB + lq*4);  // r-wave y read / hc write; +128 s

    // x stage mapping: thread -> (row, 4 floats)
    const int xr = tid >> 5;             // 0..15
    const int xc = (tid & 31) << 2;      // 0..124
    const float* xsrc = data + (size_t)(row0 + xr) * (size_t)(NT * ND) + xc;
    char* x_wr = h_lds + xr*HS + 256 + 2*xc;

    // ---------------- prologue ----------------
    *(bf16x4*)(h_lds + xr*HS + (tid & 31)*8) = (bf16x4){};   // zero y,s cols
    {
        float4 x0 = *(const float4*)xsrc;
        bf16x4 xb = { (bf16)x0.x, (bf16)x0.y, (bf16)x0.z, (bf16)x0.w };
        *(bf16x4*)x_wr = xb;                                  // stage x(0)
    }
    BAR();
    f32x4 Ax0, Ax1, Cx;                  // carried x-partials (incl. bias)
    {
        Ax0 = bA[0]; Ax1 = bA[1]; Cx = bC;
        #pragma unroll
        for (int kt = 0; kt < 4; ++kt){
            bf16x8 xv = *(const bf16x8*)(h_x_rd + kt*64);
            Ax0 = mfma16(wAx[kt*2+0], xv, Ax0);
            Ax1 = mfma16(wAx[kt*2+1], xv, Ax1);
            Cx  = mfma16(wCx[kt],     xv, Cx);
        }
    }
    float4 xn = *(const float4*)(xsrc + ND);   // x(1) for first P1 publish
    f32x4 st = {0.f,0.f,0.f,0.f};              // y-state (UG) or s-state fp32
    f32x4 ug_reg = {0.f,0.f,0.f,0.f};
    bf16x8 xf0, xf1, xf2, xf3;                 // x frags cached P2 -> P3
    BAR();   // protect prologue x-reads from first P1's x(1) publish

    #pragma unroll 1
    for (int t = 0; t < NT; ++t){
        // ---- P1: A_ys(t) (acc = carried A_x(t)); publish x(t+1); prefetch ----
        {
            f32x4 a0 = Ax0, a1 = Ax1;
            #pragma unroll
            for (int kt = 0; kt < 4; ++kt){
                bf16x8 hv = *(const bf16x8*)(h_ys_rd + kt*64);
                a0 = mfma16(wAy[kt*2+0], hv, a0);
                a1 = mfma16(wAy[kt*2+1], hv, a1);
            }
            *(bf16x4*)(t_wr +  0) = tanh4(a0);
            *(bf16x4*)(t_wr + 32) = tanh4(a1);
            bf16x4 xb = { (bf16)xn.x, (bf16)xn.y, (bf16)xn.z, (bf16)xn.w };
            *(bf16x4*)x_wr = xb;                              // x(t+1) -> h
            int t2 = (t + 2 < NT) ? (t + 2) : (NT - 1);
            xn = *(const float4*)(xsrc + (size_t)t2 * ND);    // prefetch x(t+2)
        }
        BAR();

        // ---- P2: B(t); u/r; hc in place; xf reads + A_x(t+1) in shadow ----
        {
            f32x4 b0 = bB, b1 = {0.f,0.f,0.f,0.f};
            #pragma unroll
            for (int kt = 0; kt < 4; ++kt){
                bf16x8 tv = *(const bf16x8*)(t_rd + kt*64);
                if (kt & 1) b1 = mfma16(wB[kt], tv, b1);
                else        b0 = mfma16(wB[kt], tv, b0);
            }
            xf0 = *(const bf16x8*)(h_x_rd +   0);
            xf1 = *(const bf16x8*)(h_x_rd +  64);
            xf2 = *(const bf16x8*)(h_x_rd + 128);
            xf3 = *(const bf16x8*)(h_x_rd + 192);
            f32x4 ax0 = bA[0], ax1 = bA[1];
            ax0 = mfma16(wAx[0], xf0, ax0);  ax1 = mfma16(wAx[1], xf0, ax1);
            ax0 = mfma16(wAx[2], xf1, ax0);  ax1 = mfma16(wAx[3], xf1, ax1);
            ax0 = mfma16(wAx[4], xf2, ax0);  ax1 = mfma16(wAx[5], xf2, ax1);
            ax0 = mfma16(wAx[6], xf3, ax0);  ax1 = mfma16(wAx[7], xf3, ax1);
            Ax0 = ax0; Ax1 = ax1;
            f32x4 bs = b0 + b1;
            float g0 = fast_sigmoid(bs[0]);
            float g1 = fast_sigmoid(bs[1]);
            float g2 = fast_sigmoid(bs[2]);
            float g3 = fast_sigmoid(bs[3]);
            if (UG){
                ug_reg[0] = g0; ug_reg[1] = g1; ug_reg[2] = g2; ug_reg[3] = g3;
                *(f32x4*)&u_lds[lc][fB + lq*4] = ug_reg;
            } else {
                bf16x4 yv = *(const bf16x4*)(ys_rw);
                bf16x4 sv = *(const bf16x4*)(ys_rw + 128);
                bf16x4 hy = { (bf16)((float)yv[0]*g0), (bf16)((float)yv[1]*g1),
                              (bf16)((float)yv[2]*g2), (bf16)((float)yv[3]*g3) };
                bf16x4 hs = { (bf16)((float)sv[0]*g0), (bf16)((float)sv[1]*g1),
                              (bf16)((float)sv[2]*g2), (bf16)((float)sv[3]*g3) };
                *(bf16x4*)(ys_rw)       = hy;     // hc y*r over y cols
                *(bf16x4*)(ys_rw + 128) = hs;     // hc s*r over s cols
            }
        }
        BAR();

        // ---- P3: C_hc(t) (acc = carried C_x(t)); C_x(t+1) on cached xf ----
        {
            f32x4 c0 = Cx, c1 = {0.f,0.f,0.f,0.f};
            #pragma unroll
            for (int kt = 0; kt < 4; ++kt){
                bf16x8 hv = *(const bf16x8*)(h_ys_rd + kt*64);
                if (kt & 1) c1 = mfma16(wCh[kt], hv, c1);
                else        c0 = mfma16(wCh[kt], hv, c0);
            }
            f32x4 cx = bC;
            cx = mfma16(wCx[0], xf0, cx);
            cx = mfma16(wCx[1], xf1, cx);
            cx = mfma16(wCx[2], xf2, cx);
            cx = mfma16(wCx[3], xf3, cx);
            Cx = cx;
            f32x4 cs = c0 + c1;
            *(bf16x4*)tn_wr = tanh4(cs);
        }
        BAR();

        // ---- P4: D(t); EMA in fp32 regs; publish y,s bf16 ----
        {
            f32x4 d0 = bD, d1 = {0.f,0.f,0.f,0.f};
            #pragma unroll
            for (int kt = 0; kt < 4; ++kt){
                bf16x8 tv = *(const bf16x8*)(tn_rd + kt*64);
                if (kt & 1) d1 = mfma16(wD[kt], tv, d1);
                else        d0 = mfma16(wD[kt], tv, d0);
            }
            f32x4 ds = d0 + d1;
            f32x4 uu = UG ? ug_reg : *(const f32x4*)&u_lds[lc][fB + lq*4];
            #pragma unroll
            for (int i = 0; i < 4; ++i){
                float v = UG ? ds[i] : fabsf(ds[i]);
                st[i] = fmaf(uu[i], st[i] - v, v);
            }
            bf16x4 hn = { (bf16)st[0], (bf16)st[1], (bf16)st[2], (bf16)st[3] };
            *(bf16x4*)h_st_wr = hn;
        }
        BAR();
    }

    // ---------------- output: yT (4096x64) then sT (4096x64), fp32 ----------
    {
        size_t gr = (size_t)(row0 + lc);
        float4 v = make_float4(st[0], st[1], st[2], st[3]);
        if (UG) *(float4*)&out[gr*64 + fD + lq*4] = v;
        else    *(float4*)&out[(size_t)NB*64 + gr*64 + (fD - 64) + lq*4] = v;
    }
}

extern "C" void kernel_launch(void* const* d_in, const int* in_sizes, int n_in,
                              void* d_out, int out_size, void* d_ws, size_t ws_size,
                              hipStream_t stream) {
    const float* data  = (const float*)d_in[0];
    // d_in[1] = time_steps — unused by the reference computation
    const float* ug_w1 = (const float*)d_in[2];
    const float* ug_b1 = (const float*)d_in[3];
    const float* ug_w2 = (const float*)d_in[4];
    const float* ug_b2 = (const float*)d_in[5];
    const float* rg_w1 = (const float*)d_in[6];
    const float* rg_b1 = (const float*)d_in[7];
    const float* rg_w2 = (const float*)d_in[8];
    const float* rg_b2 = (const float*)d_in[9];
    const float* ns_w1 = (const float*)d_in[10];
    const float* ns_b1 = (const float*)d_in[11];
    const float* ns_w2 = (const float*)d_in[12];
    const float* ns_b2 = (const float*)d_in[13];

    hipLaunchKernelGGL(vae_rnn, dim3(NB/16), dim3(512), 0, stream,
                       data, ug_w1, ug_b1, ug_w2, ug_b2,
                       rg_w1, rg_b1, rg_w2, rg_b2,
                       ns_w1, ns_b1, ns_w2, ns_b2,
                       (float*)d_out);
}